// Round 3
// baseline (1221.660 us; speedup 1.0000x reference)
//
#include <hip/hip_runtime.h>
#include <hip/hip_bf16.h>
#include <math.h>

#define NNODES 50000
#define NEDGES 800000
#define DIN 768
#define DH 256
#define NCLS 4
#define NGRAPHS 64

typedef __bf16 bf16x8 __attribute__((ext_vector_type(8)));
typedef float f32x4 __attribute__((ext_vector_type(4)));

static __device__ __forceinline__ float bf2f(unsigned short u) {
    union { unsigned u32; float f; } v; v.u32 = ((unsigned)u) << 16; return v.f;
}
static __device__ __forceinline__ unsigned short f2bf(float f) {
    union { float f; unsigned u; } v; v.f = f;
    unsigned r = (v.u + 0x7fffu + ((v.u >> 16) & 1u)) >> 16;
    return (unsigned short)r;
}
static __device__ __forceinline__ void unpack4(uint2 u, float* f) {
    f[0] = bf2f((unsigned short)(u.x & 0xffff));
    f[1] = bf2f((unsigned short)(u.x >> 16));
    f[2] = bf2f((unsigned short)(u.y & 0xffff));
    f[3] = bf2f((unsigned short)(u.y >> 16));
}

// ---------------- dtype detection ----------------
// If x is truly fp32, its odd u16 halves are random mantissa bits -> ~37%
// decode (as bf16) to |v|>1e10 or NaN. If truly bf16 (N(0,1)), none do.
__global__ void detect_dtype(const unsigned short* __restrict__ x, int* __restrict__ flag) {
    __shared__ int cnt_s;
    if (threadIdx.x == 0) cnt_s = 0;
    __syncthreads();
    int c = 0;
    for (int i = 0; i < 16; ++i) {
        float v = bf2f(x[threadIdx.x * 16 + i]);
        if (!(fabsf(v) < 1e10f)) c++;  // catches huge, inf, NaN
    }
    atomicAdd(&cnt_s, c);
    __syncthreads();
    if (threadIdx.x == 0) flag[0] = (cnt_s > 32) ? 1 : 0;  // 1 => inputs are fp32
}

// canonicalize a float array (fp32 or bf16 per flag) into bf16
__global__ void canon(const void* __restrict__ src, unsigned short* __restrict__ dst,
                      int n, const int* __restrict__ flag) {
    int i = blockIdx.x * 256 + threadIdx.x;
    if (i < n) {
        if (flag[0]) dst[i] = f2bf(((const float*)src)[i]);
        else dst[i] = ((const unsigned short*)src)[i];
    }
}

// ---------------- diagnostic sentinel (ws too small) ----------------
__global__ void fill_sentinel(float* out, int n) {
    int i = blockIdx.x * 256 + threadIdx.x;
    if (i < n) out[i] = 1000.0f;  // reads ~1000 under fp32 AND bf16 interpretation
}

// ---------------- small prep kernels ----------------
__global__ void transpose_bf16(const unsigned short* __restrict__ src,
                               unsigned short* __restrict__ dst, int R, int C) {
    int idx = blockIdx.x * 256 + threadIdx.x;
    if (idx < R * C) {
        int r = idx / C, c = idx % C;
        dst[(size_t)c * R + r] = src[idx];
    }
}

__global__ void count_edges(const int* __restrict__ ei, int* __restrict__ cnt) {
    int e = blockIdx.x * 256 + threadIdx.x;
    if (e < NEDGES) atomicAdd(&cnt[ei[NEDGES + e]], 1);
}

__global__ __launch_bounds__(1024) void scan_rowptr(const int* __restrict__ cnt,
                                                    int* __restrict__ rowptr) {
    __shared__ int tmp[1024];
    const int t = threadIdx.x;
    int base = 0;
    const int nchunk = (NNODES + 1023) / 1024;
    for (int c = 0; c < nchunk; ++c) {
        int i = c * 1024 + t;
        int v = (i < NNODES) ? cnt[i] : 0;
        tmp[t] = v;
        __syncthreads();
        for (int off = 1; off < 1024; off <<= 1) {
            int a = (t >= off) ? tmp[t - off] : 0;
            __syncthreads();
            if (t >= off) tmp[t] += a;
            __syncthreads();
        }
        if (i < NNODES) rowptr[i] = base + tmp[t] - v;
        int total = tmp[1023];
        __syncthreads();
        base += total;
    }
    if (t == 0) rowptr[NNODES] = base;
}

__global__ void calc_dinv(const int* __restrict__ cnt, float* __restrict__ dinv) {
    int i = blockIdx.x * 256 + threadIdx.x;
    if (i < NNODES) dinv[i] = rsqrtf((float)(1 + cnt[i]));  // +1 self-loop
}

__global__ void fill_csr(const int* __restrict__ ei, const int* __restrict__ rowptr,
                         int* __restrict__ cursor, int* __restrict__ csrc) {
    int e = blockIdx.x * 256 + threadIdx.x;
    if (e < NEDGES) {
        int s = ei[e];
        int d = ei[NEDGES + e];
        int pos = rowptr[d] + atomicAdd(&cursor[d], 1);
        csrc[pos] = s;
    }
}

// ---------------- GEMM: C[M,N]=A[M,K]@B[K,N], Bt=[N,K] pre-transposed ----------------
#define BM 128
#define BN 128
#define BK 32
#define LDSS 40   // LDS row stride in bf16 units (pad 32->40; 80B rows, 16B aligned)

__global__ __launch_bounds__(256) void gemm_bf16_tn(
    const void* __restrict__ Araw,          // [M,K] bf16 or fp32 (per flag)
    const int* __restrict__ dflag, int use_flag,
    const unsigned short* __restrict__ Bt,  // [N,K] bf16
    const unsigned short* __restrict__ bias,// [N] bf16 or nullptr
    unsigned short* __restrict__ C,         // [M,N] bf16
    int M, int N, int K)
{
    __shared__ unsigned short As[BM * LDSS];
    __shared__ unsigned short Bs[BN * LDSS];
    const int a_fp32 = use_flag ? dflag[0] : 0;
    const int m0 = blockIdx.x * BM;
    const int n0 = blockIdx.y * BN;
    const int t = threadIdx.x;
    const int wave = t >> 6, lane = t & 63;
    const int quad = lane >> 4, l16 = lane & 15;
    const int wm = (wave >> 1) << 6;
    const int wn = (wave & 1) << 6;

    f32x4 acc[4][4];
#pragma unroll
    for (int i = 0; i < 4; i++)
#pragma unroll
        for (int j = 0; j < 4; j++) acc[i][j] = (f32x4){0.f, 0.f, 0.f, 0.f};

    const int lrow = t >> 2;
    const int lcg = t & 3;

    for (int k0 = 0; k0 < K; k0 += BK) {
#pragma unroll
        for (int p = 0; p < 2; ++p) {
            int row = lrow + p * 64;
            int gm = m0 + row;
            uint4 av = make_uint4(0u, 0u, 0u, 0u);
            if (gm < M) {
                if (a_fp32) {
                    const float* Af = (const float*)Araw + (size_t)gm * K + k0 + lcg * 8;
                    float4 f0 = *(const float4*)Af;
                    float4 f1 = *(const float4*)(Af + 4);
                    av.x = (unsigned)f2bf(f0.x) | ((unsigned)f2bf(f0.y) << 16);
                    av.y = (unsigned)f2bf(f0.z) | ((unsigned)f2bf(f0.w) << 16);
                    av.z = (unsigned)f2bf(f1.x) | ((unsigned)f2bf(f1.y) << 16);
                    av.w = (unsigned)f2bf(f1.z) | ((unsigned)f2bf(f1.w) << 16);
                } else {
                    av = *(const uint4*)((const unsigned short*)Araw + (size_t)gm * K + k0 + lcg * 8);
                }
            }
            *(uint4*)(&As[row * LDSS + lcg * 8]) = av;
            int gn = n0 + row;  // N==256 always in range here
            uint4 bv = *(const uint4*)(Bt + (size_t)gn * K + k0 + lcg * 8);
            *(uint4*)(&Bs[row * LDSS + lcg * 8]) = bv;
        }
        __syncthreads();
        bf16x8 af[4], bfv[4];
#pragma unroll
        for (int i = 0; i < 4; i++)
            af[i] = *(const bf16x8*)(&As[(wm + 16 * i + l16) * LDSS + quad * 8]);
#pragma unroll
        for (int j = 0; j < 4; j++)
            bfv[j] = *(const bf16x8*)(&Bs[(wn + 16 * j + l16) * LDSS + quad * 8]);
#pragma unroll
        for (int i = 0; i < 4; i++)
#pragma unroll
            for (int j = 0; j < 4; j++)
                acc[i][j] = __builtin_amdgcn_mfma_f32_16x16x32_bf16(af[i], bfv[j], acc[i][j], 0, 0, 0);
        __syncthreads();
    }
#pragma unroll
    for (int i = 0; i < 4; i++) {
#pragma unroll
        for (int j = 0; j < 4; j++) {
            int gc = n0 + wn + 16 * j + l16;
            float bv = bias ? bf2f(bias[gc]) : 0.f;
#pragma unroll
            for (int r = 0; r < 4; r++) {
                int gr = m0 + wm + 16 * i + quad * 4 + r;
                if (gr < M) C[(size_t)gr * N + gc] = f2bf(acc[i][j][r] + bv);
            }
        }
    }
}

// ------- fused: CSR gather + self-loop + bias + residual + ReLU + LayerNorm -------
__global__ __launch_bounds__(256) void aggregate_ln(
    const int* __restrict__ rowptr, const int* __restrict__ csrc,
    const float* __restrict__ dinv, const unsigned short* __restrict__ m,
    const unsigned short* __restrict__ convB,
    const unsigned short* __restrict__ lnG, const unsigned short* __restrict__ lnB,
    unsigned short* __restrict__ h)
{
    const int wave = threadIdx.x >> 6, lane = threadIdx.x & 63;
    const int node = blockIdx.x * 4 + wave;
    if (node >= NNODES) return;
    const float di = dinv[node];
    const size_t base = (size_t)node * DH + lane * 4;

    // self-loop contribution m[node] * dinv^2
    float v[4];
    unpack4(*(const uint2*)(m + base), v);
    const float selfn = di * di;
    v[0] *= selfn; v[1] *= selfn; v[2] *= selfn; v[3] *= selfn;

    const int k0 = rowptr[node], k1 = rowptr[node + 1];
    int k = k0;
    int sNext = (k < k1) ? csrc[k] : 0;
    while (k < k1) {
        const int s = sNext;
        const uint2 mr = *(const uint2*)(m + (size_t)s * DH + lane * 4);
        const float nrm = dinv[s] * di;
        ++k;
        if (k < k1) sNext = csrc[k];
        float mv[4];
        unpack4(mr, mv);
        v[0] += mv[0] * nrm;
        v[1] += mv[1] * nrm;
        v[2] += mv[2] * nrm;
        v[3] += mv[3] * nrm;
    }

    // + bias + residual, ReLU
    float hv[4], cv[4];
    unpack4(*(const uint2*)(h + base), hv);
    unpack4(*(const uint2*)(convB + lane * 4), cv);
    float s1 = 0.f, s2 = 0.f;
#pragma unroll
    for (int j = 0; j < 4; j++) {
        v[j] = fmaxf(v[j] + cv[j] + hv[j], 0.f);
        s1 += v[j];
        s2 += v[j] * v[j];
    }
#pragma unroll
    for (int off = 32; off > 0; off >>= 1) {
        s1 += __shfl_xor(s1, off);
        s2 += __shfl_xor(s2, off);
    }
    const float mu = s1 * (1.f / 256.f);
    const float var = s2 * (1.f / 256.f) - mu * mu;
    const float rs = rsqrtf(var + 1e-5f);
    float gv[4], bv[4];
    unpack4(*(const uint2*)(lnG + lane * 4), gv);
    unpack4(*(const uint2*)(lnB + lane * 4), bv);
    uint2 outp;
    unsigned short o0 = f2bf((v[0] - mu) * rs * gv[0] + bv[0]);
    unsigned short o1 = f2bf((v[1] - mu) * rs * gv[1] + bv[1]);
    unsigned short o2 = f2bf((v[2] - mu) * rs * gv[2] + bv[2]);
    unsigned short o3 = f2bf((v[3] - mu) * rs * gv[3] + bv[3]);
    outp.x = (unsigned)o0 | ((unsigned)o1 << 16);
    outp.y = (unsigned)o2 | ((unsigned)o3 << 16);
    *(uint2*)(h + base) = outp;
}

// ---------------- pooling (batch is sorted -> contiguous ranges) ----------------
__global__ void range_init(int* s, int* e) {
    int t = threadIdx.x;
    if (t < NGRAPHS) { s[t] = NNODES; e[t] = 0; }
}
__global__ void range_scan(const int* __restrict__ batch, int* __restrict__ s,
                           int* __restrict__ e) {
    int i = blockIdx.x * 256 + threadIdx.x;
    if (i < NNODES) {
        int b = batch[i];
        atomicMin(&s[b], i);
        atomicMax(&e[b], i + 1);
    }
}
__global__ __launch_bounds__(256) void pool_max(
    const unsigned short* __restrict__ h, const int* __restrict__ s,
    const int* __restrict__ e, float* __restrict__ g)
{
    const int b = blockIdx.x, f = threadIdx.x;
    const int i0 = s[b], i1 = e[b];
    float mx = -INFINITY;
    for (int i = i0; i < i1; ++i) mx = fmaxf(mx, bf2f(h[(size_t)i * DH + f]));
    g[b * DH + f] = mx;
}

// ---------------- classifier: out = relu(g@W1+b1)@W2+b2 ----------------
__global__ __launch_bounds__(256) void classifier(
    const float* __restrict__ g, const unsigned short* __restrict__ W1,
    const unsigned short* __restrict__ b1, const unsigned short* __restrict__ W2,
    const unsigned short* __restrict__ b2, void* __restrict__ outv,
    const int* __restrict__ flag)
{
    __shared__ float gz[DH];
    __shared__ float zz[DH];
    const int b = blockIdx.x, t = threadIdx.x;
    gz[t] = g[b * DH + t];
    __syncthreads();
    float s = bf2f(b1[t]);
    for (int k = 0; k < DH; ++k) s += gz[k] * bf2f(W1[k * DH + t]);
    zz[t] = fmaxf(s, 0.f);
    __syncthreads();
    if (t < NCLS) {
        float s2 = bf2f(b2[t]);
        for (int k = 0; k < DH; ++k) s2 += zz[k] * bf2f(W2[k * NCLS + t]);
        if (flag[0]) ((float*)outv)[b * NCLS + t] = s2;
        else ((unsigned short*)outv)[b * NCLS + t] = f2bf(s2);
    }
}

extern "C" void kernel_launch(void* const* d_in, const int* in_sizes, int n_in,
                              void* d_out, int out_size, void* d_ws, size_t ws_size,
                              hipStream_t stream)
{
    const void* x      = d_in[0];
    const int* ei      = (const int*)d_in[1];
    const int* batch   = (const int*)d_in[2];
    const void* Win    = d_in[3];
    const void* b_in   = d_in[4];
    const void* convW  = d_in[5];
    const void* convB  = d_in[6];
    const void* lnG    = d_in[7];
    const void* lnB    = d_in[8];
    const void* W1     = d_in[9];
    const void* b1     = d_in[10];
    const void* W2     = d_in[11];
    const void* b2     = d_in[12];

    // workspace layout (bytes), 16B aligned
    char* ws = (char*)d_ws;
    unsigned short* h   = (unsigned short*)(ws + 0);          // 25,600,000
    unsigned short* m   = (unsigned short*)(ws + 25600000);   // 25,600,000
    int* csrc           = (int*)(ws + 51200000);              //  3,200,000
    int* rowptr         = (int*)(ws + 54400000);              //    200,016
    int* cnt            = (int*)(ws + 54600016);              //    200,000
    int* cursor         = (int*)(ws + 54800016);              //    200,000
    float* dinv         = (float*)(ws + 55000016);            //    200,000
    unsigned short* cw  = (unsigned short*)(ws + 55200016);   //    925,200 (canonical weights)
    unsigned short* WinT= (unsigned short*)(ws + 56125216);   //    393,216
    unsigned short* WcT = (unsigned short*)(ws + 56518432);   //    393,216
    float* g            = (float*)(ws + 56911648);            //     65,536
    int* gs             = (int*)(ws + 56977184);              //        256
    int* ge             = (int*)(ws + 56977440);              //        256
    int* flag           = (int*)(ws + 56977696);              //         16
    const size_t NEED   = 56977712;
    if (ws_size < NEED) {
        fill_sentinel<<<(out_size / 2 + 255) / 256, 256, 0, stream>>>((float*)d_out, out_size / 2);
        return;
    }

    // canonical weight sub-offsets (bf16 element offsets within cw)
    unsigned short* cWin   = cw + 0;        // 196608
    unsigned short* cConvW = cw + 196608;   // 196608
    unsigned short* cBin   = cw + 393216;   // 256
    unsigned short* cConvB = cw + 393472;   // 768
    unsigned short* cLnG   = cw + 394240;   // 768
    unsigned short* cLnB   = cw + 395008;   // 768
    unsigned short* cW1    = cw + 395776;   // 65536
    unsigned short* cW2    = cw + 461312;   // 1024
    unsigned short* cB1    = cw + 462336;   // 256
    unsigned short* cB2    = cw + 462592;   // 4

    // ---- dtype detection ----
    detect_dtype<<<1, 256, 0, stream>>>((const unsigned short*)x, flag);

    // ---- CSR build (dst-sorted) + degrees ----
    hipMemsetAsync(cnt, 0, 400000, stream);  // cnt AND cursor (contiguous)
    count_edges<<<(NEDGES + 255) / 256, 256, 0, stream>>>(ei, cnt);
    scan_rowptr<<<1, 1024, 0, stream>>>(cnt, rowptr);
    calc_dinv<<<(NNODES + 255) / 256, 256, 0, stream>>>(cnt, dinv);
    fill_csr<<<(NEDGES + 255) / 256, 256, 0, stream>>>(ei, rowptr, cursor, csrc);

    // ---- canonicalize weights to bf16 ----
    canon<<<(196608 + 255) / 256, 256, 0, stream>>>(Win, cWin, 196608, flag);
    canon<<<(196608 + 255) / 256, 256, 0, stream>>>(convW, cConvW, 196608, flag);
    canon<<<1, 256, 0, stream>>>(b_in, cBin, 256, flag);
    canon<<<3, 256, 0, stream>>>(convB, cConvB, 768, flag);
    canon<<<3, 256, 0, stream>>>(lnG, cLnG, 768, flag);
    canon<<<3, 256, 0, stream>>>(lnB, cLnB, 768, flag);
    canon<<<(65536 + 255) / 256, 256, 0, stream>>>(W1, cW1, 65536, flag);
    canon<<<4, 256, 0, stream>>>(W2, cW2, 1024, flag);
    canon<<<1, 256, 0, stream>>>(b1, cB1, 256, flag);
    canon<<<1, 256, 0, stream>>>(b2, cB2, 4, flag);

    // ---- weight transposes for K-major MFMA B fragments ----
    transpose_bf16<<<(DIN * DH + 255) / 256, 256, 0, stream>>>(cWin, WinT, DIN, DH);
    for (int i = 0; i < 3; i++)
        transpose_bf16<<<(DH * DH + 255) / 256, 256, 0, stream>>>(
            cConvW + i * DH * DH, WcT + i * DH * DH, DH, DH);

    // ---- h = x @ W_in + b_in ----
    dim3 gg((NNODES + BM - 1) / BM, DH / BN);
    gemm_bf16_tn<<<gg, 256, 0, stream>>>(x, flag, 1, WinT, cBin, h, NNODES, DH, DIN);

    // ---- 3 GCN layers ----
    for (int i = 0; i < 3; i++) {
        gemm_bf16_tn<<<gg, 256, 0, stream>>>(h, flag, 0, WcT + i * DH * DH, nullptr, m,
                                             NNODES, DH, DH);
        aggregate_ln<<<(NNODES + 3) / 4, 256, 0, stream>>>(
            rowptr, csrc, dinv, m, cConvB + i * DH, cLnG + i * DH, cLnB + i * DH, h);
    }

    // ---- global max pool + classifier ----
    range_init<<<1, 64, 0, stream>>>(gs, ge);
    range_scan<<<(NNODES + 255) / 256, 256, 0, stream>>>(batch, gs, ge);
    pool_max<<<NGRAPHS, 256, 0, stream>>>(h, gs, ge, g);
    classifier<<<NGRAPHS, 256, 0, stream>>>(g, cW1, cB1, cW2, cB2, d_out, flag);
}

// Round 4
// 731.133 us; speedup vs baseline: 1.6709x; 1.6709x over previous
//
#include <hip/hip_runtime.h>
#include <hip/hip_bf16.h>
#include <math.h>

#define NNODES 50000
#define NEDGES 800000
#define DIN 768
#define DH 256
#define NCLS 4
#define NGRAPHS 64
#define SCAN_BLOCKS 196   // ceil(NNODES/256)

typedef __bf16 bf16x8 __attribute__((ext_vector_type(8)));
typedef float f32x4 __attribute__((ext_vector_type(4)));

static __device__ __forceinline__ float bf2f(unsigned short u) {
    union { unsigned u32; float f; } v; v.u32 = ((unsigned)u) << 16; return v.f;
}
static __device__ __forceinline__ unsigned short f2bf(float f) {
    union { float f; unsigned u; } v; v.f = f;
    unsigned r = (v.u + 0x7fffu + ((v.u >> 16) & 1u)) >> 16;
    return (unsigned short)r;
}
static __device__ __forceinline__ void unpack8(uint4 u, float* f) {
    f[0] = bf2f((unsigned short)(u.x & 0xffff)); f[1] = bf2f((unsigned short)(u.x >> 16));
    f[2] = bf2f((unsigned short)(u.y & 0xffff)); f[3] = bf2f((unsigned short)(u.y >> 16));
    f[4] = bf2f((unsigned short)(u.z & 0xffff)); f[5] = bf2f((unsigned short)(u.z >> 16));
    f[6] = bf2f((unsigned short)(u.w & 0xffff)); f[7] = bf2f((unsigned short)(u.w >> 16));
}

// ---------------- dtype detection (fp32 vs bf16 inputs) ----------------
__global__ void detect_dtype(const unsigned short* __restrict__ x, int* __restrict__ flag) {
    __shared__ int cnt_s;
    if (threadIdx.x == 0) cnt_s = 0;
    __syncthreads();
    int c = 0;
    for (int i = 0; i < 16; ++i) {
        float v = bf2f(x[threadIdx.x * 16 + i]);
        if (!(fabsf(v) < 1e10f)) c++;
    }
    atomicAdd(&cnt_s, c);
    __syncthreads();
    if (threadIdx.x == 0) flag[0] = (cnt_s > 32) ? 1 : 0;  // 1 => fp32
}

static __device__ __forceinline__ unsigned short cload(const void* src, int i, int fp32) {
    return fp32 ? f2bf(((const float*)src)[i]) : ((const unsigned short*)src)[i];
}

// ---------------- fused small-weight canonicalization ----------------
__global__ void canon_small(const void* b_in, const void* convB, const void* lnG,
                            const void* lnB, const void* W1, const void* W2,
                            const void* b1, const void* b2,
                            unsigned short* __restrict__ dst, const int* __restrict__ flag) {
    int i = blockIdx.x * 256 + threadIdx.x;
    if (i >= 69380) return;
    const int fp32 = flag[0];
    int j = i;
    if (j < 256)  { dst[i] = cload(b_in, j, fp32); return; }  j -= 256;
    if (j < 768)  { dst[i] = cload(convB, j, fp32); return; } j -= 768;
    if (j < 768)  { dst[i] = cload(lnG, j, fp32); return; }   j -= 768;
    if (j < 768)  { dst[i] = cload(lnB, j, fp32); return; }   j -= 768;
    if (j < 65536){ dst[i] = cload(W1, j, fp32); return; }    j -= 65536;
    if (j < 1024) { dst[i] = cload(W2, j, fp32); return; }    j -= 1024;
    if (j < 256)  { dst[i] = cload(b1, j, fp32); return; }    j -= 256;
    dst[i] = cload(b2, j, fp32);
}

// ---------------- fused convert+transpose for GEMM B operands ----------------
__global__ void transpose_win(const void* __restrict__ src, unsigned short* __restrict__ dst,
                              const int* __restrict__ flag) {
    int idx = blockIdx.x * 256 + threadIdx.x;
    if (idx < DIN * DH) {
        int r = idx / DH, c = idx % DH;
        dst[(size_t)c * DIN + r] = cload(src, idx, flag[0]);
    }
}
__global__ void transpose_convw(const void* __restrict__ src, unsigned short* __restrict__ dst,
                                const int* __restrict__ flag) {
    int idx = blockIdx.x * 256 + threadIdx.x;
    if (idx < 3 * DH * DH) {
        int l = idx >> 16, rc = idx & 65535;
        int r = rc >> 8, c = rc & 255;
        dst[(l << 16) + c * DH + r] = cload(src, idx, flag[0]);
    }
}

// ---------------- diagnostic sentinel (ws too small) ----------------
__global__ void fill_sentinel(float* out, int n) {
    int i = blockIdx.x * 256 + threadIdx.x;
    if (i < n) out[i] = 1000.0f;
}

// ---------------- CSR build ----------------
__global__ void count_edges(const int* __restrict__ ei, int* __restrict__ cnt) {
    int e = blockIdx.x * 256 + threadIdx.x;
    if (e < NEDGES) atomicAdd(&cnt[ei[NEDGES + e]], 1);
}

__global__ void scan_local(const int* __restrict__ cnt, int* __restrict__ rowptr,
                           int* __restrict__ bsum) {
    __shared__ int tmp[256];
    int i = blockIdx.x * 256 + threadIdx.x;
    int v = (i < NNODES) ? cnt[i] : 0;
    tmp[threadIdx.x] = v;
    __syncthreads();
    for (int off = 1; off < 256; off <<= 1) {
        int a = (threadIdx.x >= off) ? tmp[threadIdx.x - off] : 0;
        __syncthreads();
        tmp[threadIdx.x] += a;
        __syncthreads();
    }
    if (i < NNODES) rowptr[i] = tmp[threadIdx.x] - v;  // local exclusive
    if (threadIdx.x == 255) bsum[blockIdx.x] = tmp[255];
}
__global__ void scan_bsum(const int* __restrict__ bsum, int* __restrict__ boff) {
    __shared__ int tmp[256];
    int t = threadIdx.x;
    int v = (t < SCAN_BLOCKS) ? bsum[t] : 0;
    tmp[t] = v;
    __syncthreads();
    for (int off = 1; off < 256; off <<= 1) {
        int a = (t >= off) ? tmp[t - off] : 0;
        __syncthreads();
        tmp[t] += a;
        __syncthreads();
    }
    if (t < SCAN_BLOCKS) boff[t] = tmp[t] - v;
}
__global__ void scan_finish(int* __restrict__ rowptr, const int* __restrict__ boff,
                            const int* __restrict__ cnt, float* __restrict__ dinv) {
    int i = blockIdx.x * 256 + threadIdx.x;
    if (i < NNODES) {
        rowptr[i] += boff[blockIdx.x];
        dinv[i] = rsqrtf((float)(1 + cnt[i]));  // +1 self-loop
    }
    if (i == 0) rowptr[NNODES] = NEDGES;
}

__global__ void fill_csr(const int* __restrict__ ei, const int* __restrict__ rowptr,
                         int* __restrict__ cursor, int* __restrict__ csrc) {
    int e = blockIdx.x * 256 + threadIdx.x;
    if (e < NEDGES) {
        int s = ei[e];
        int d = ei[NEDGES + e];
        int pos = rowptr[d] + atomicAdd(&cursor[d], 1);
        csrc[pos] = s;
    }
}

// ---------------- GEMM: C[M,N]=A[M,K]@B[K,N], Bt=[N,K] pre-transposed ----------------
#define BM 128
#define BN 128
#define BK 32
#define LDSS 40

__global__ __launch_bounds__(256) void gemm_bf16_tn(
    const void* __restrict__ Araw, const int* __restrict__ dflag, int use_flag,
    const unsigned short* __restrict__ Bt, const unsigned short* __restrict__ bias,
    unsigned short* __restrict__ C, int M, int N, int K)
{
    __shared__ unsigned short As[BM * LDSS];
    __shared__ unsigned short Bs[BN * LDSS];
    const int a_fp32 = use_flag ? dflag[0] : 0;
    const int m0 = blockIdx.x * BM;
    const int n0 = blockIdx.y * BN;
    const int t = threadIdx.x;
    const int wave = t >> 6, lane = t & 63;
    const int quad = lane >> 4, l16 = lane & 15;
    const int wm = (wave >> 1) << 6;
    const int wn = (wave & 1) << 6;

    f32x4 acc[4][4];
#pragma unroll
    for (int i = 0; i < 4; i++)
#pragma unroll
        for (int j = 0; j < 4; j++) acc[i][j] = (f32x4){0.f, 0.f, 0.f, 0.f};

    const int lrow = t >> 2;
    const int lcg = t & 3;

    for (int k0 = 0; k0 < K; k0 += BK) {
#pragma unroll
        for (int p = 0; p < 2; ++p) {
            int row = lrow + p * 64;
            int gm = m0 + row;
            uint4 av = make_uint4(0u, 0u, 0u, 0u);
            if (gm < M) {
                if (a_fp32) {
                    const float* Af = (const float*)Araw + (size_t)gm * K + k0 + lcg * 8;
                    float4 f0 = *(const float4*)Af;
                    float4 f1 = *(const float4*)(Af + 4);
                    av.x = (unsigned)f2bf(f0.x) | ((unsigned)f2bf(f0.y) << 16);
                    av.y = (unsigned)f2bf(f0.z) | ((unsigned)f2bf(f0.w) << 16);
                    av.z = (unsigned)f2bf(f1.x) | ((unsigned)f2bf(f1.y) << 16);
                    av.w = (unsigned)f2bf(f1.z) | ((unsigned)f2bf(f1.w) << 16);
                } else {
                    av = *(const uint4*)((const unsigned short*)Araw + (size_t)gm * K + k0 + lcg * 8);
                }
            }
            *(uint4*)(&As[row * LDSS + lcg * 8]) = av;
            int gn = n0 + row;
            uint4 bv = *(const uint4*)(Bt + (size_t)gn * K + k0 + lcg * 8);
            *(uint4*)(&Bs[row * LDSS + lcg * 8]) = bv;
        }
        __syncthreads();
        bf16x8 af[4], bfv[4];
#pragma unroll
        for (int i = 0; i < 4; i++)
            af[i] = *(const bf16x8*)(&As[(wm + 16 * i + l16) * LDSS + quad * 8]);
#pragma unroll
        for (int j = 0; j < 4; j++)
            bfv[j] = *(const bf16x8*)(&Bs[(wn + 16 * j + l16) * LDSS + quad * 8]);
#pragma unroll
        for (int i = 0; i < 4; i++)
#pragma unroll
            for (int j = 0; j < 4; j++)
                acc[i][j] = __builtin_amdgcn_mfma_f32_16x16x32_bf16(af[i], bfv[j], acc[i][j], 0, 0, 0);
        __syncthreads();
    }
#pragma unroll
    for (int i = 0; i < 4; i++) {
#pragma unroll
        for (int j = 0; j < 4; j++) {
            int gc = n0 + wn + 16 * j + l16;
            float bv = bias ? bf2f(bias[gc]) : 0.f;
#pragma unroll
            for (int r = 0; r < 4; r++) {
                int gr = m0 + wm + 16 * i + quad * 4 + r;
                if (gr < M) C[(size_t)gr * N + gc] = f2bf(acc[i][j][r] + bv);
            }
        }
    }
}

// ------- fused: CSR gather + self-loop + bias + residual + ReLU + LayerNorm -------
// 2 nodes per wave: lanes 0-31 -> node A, 32-63 -> node B; 16 B/lane row loads.
__global__ __launch_bounds__(256) void aggregate_ln(
    const int* __restrict__ rowptr, const int* __restrict__ csrc,
    const float* __restrict__ dinv, const unsigned short* __restrict__ m,
    const unsigned short* __restrict__ convB,
    const unsigned short* __restrict__ lnG, const unsigned short* __restrict__ lnB,
    unsigned short* __restrict__ h)
{
    const int half = threadIdx.x >> 5;      // 0..7
    const int lane = threadIdx.x & 31;
    const int node = blockIdx.x * 8 + half;  // NNODES % 8 == 0
    const float di = dinv[node];
    const size_t base = (size_t)node * DH + lane * 8;

    float v[8];
    unpack8(*(const uint4*)(m + base), v);
    const float selfn = di * di;
#pragma unroll
    for (int j = 0; j < 8; j++) v[j] *= selfn;

    const int k0 = rowptr[node], k1 = rowptr[node + 1];
    int k = k0;
    int sNext = (k < k1) ? csrc[k] : 0;
    while (k < k1) {
        const int s = sNext;
        const uint4 mr = *(const uint4*)(m + (size_t)s * DH + lane * 8);
        const float nrm = dinv[s] * di;
        ++k;
        if (k < k1) sNext = csrc[k];
        float mv[8];
        unpack8(mr, mv);
#pragma unroll
        for (int j = 0; j < 8; j++) v[j] += mv[j] * nrm;
    }

    float hv[8], cv[8];
    unpack8(*(const uint4*)(h + base), hv);
    unpack8(*(const uint4*)(convB + lane * 8), cv);
    float s1 = 0.f, s2 = 0.f;
#pragma unroll
    for (int j = 0; j < 8; j++) {
        v[j] = fmaxf(v[j] + cv[j] + hv[j], 0.f);
        s1 += v[j];
        s2 += v[j] * v[j];
    }
#pragma unroll
    for (int off = 16; off > 0; off >>= 1) {
        s1 += __shfl_xor(s1, off, 32);
        s2 += __shfl_xor(s2, off, 32);
    }
    const float mu = s1 * (1.f / 256.f);
    const float var = s2 * (1.f / 256.f) - mu * mu;
    const float rs = rsqrtf(var + 1e-5f);
    float gv[8], bv[8];
    unpack8(*(const uint4*)(lnG + lane * 8), gv);
    unpack8(*(const uint4*)(lnB + lane * 8), bv);
    unsigned short o[8];
#pragma unroll
    for (int j = 0; j < 8; j++) o[j] = f2bf((v[j] - mu) * rs * gv[j] + bv[j]);
    uint4 outp;
    outp.x = (unsigned)o[0] | ((unsigned)o[1] << 16);
    outp.y = (unsigned)o[2] | ((unsigned)o[3] << 16);
    outp.z = (unsigned)o[4] | ((unsigned)o[5] << 16);
    outp.w = (unsigned)o[6] | ((unsigned)o[7] << 16);
    *(uint4*)(h + base) = outp;
}

// ---------------- pooling: batch sorted -> boundary detection, no atomics ----------------
__global__ void find_bounds(const int* __restrict__ batch, int* __restrict__ s) {
    int i = blockIdx.x * 256 + threadIdx.x;
    if (i >= NNODES) return;
    int b = batch[i];
    int bp = (i == 0) ? -1 : batch[i - 1];
    for (int g = bp + 1; g <= b; ++g) s[g] = i;
    if (i == NNODES - 1)
        for (int g = b + 1; g <= NGRAPHS; ++g) s[g] = NNODES;
}

#define PSPLIT 8
__global__ __launch_bounds__(256) void pool_partial(
    const unsigned short* __restrict__ h, const int* __restrict__ s,
    float* __restrict__ pg)
{
    const int b = blockIdx.x >> 3, split = blockIdx.x & 7, f = threadIdx.x;
    const int i0 = s[b], i1 = s[b + 1];
    const int len = i1 - i0;
    const int c0 = i0 + (int)(((long)len * split) >> 3);
    const int c1 = i0 + (int)(((long)len * (split + 1)) >> 3);
    float mx = -INFINITY;
    for (int i = c0; i < c1; ++i) mx = fmaxf(mx, bf2f(h[(size_t)i * DH + f]));
    pg[(size_t)blockIdx.x * DH + f] = mx;
}
__global__ __launch_bounds__(256) void pool_reduce(const float* __restrict__ pg,
                                                   float* __restrict__ g) {
    const int b = blockIdx.x, f = threadIdx.x;
    float mx = -INFINITY;
#pragma unroll
    for (int j = 0; j < PSPLIT; ++j) mx = fmaxf(mx, pg[(size_t)(b * PSPLIT + j) * DH + f]);
    g[b * DH + f] = mx;
}

// ---------------- classifier: out = relu(g@W1+b1)@W2+b2 ----------------
__global__ __launch_bounds__(256) void classifier(
    const float* __restrict__ g, const unsigned short* __restrict__ W1,
    const unsigned short* __restrict__ b1, const unsigned short* __restrict__ W2,
    const unsigned short* __restrict__ b2, void* __restrict__ outv,
    const int* __restrict__ flag)
{
    __shared__ float gz[DH];
    __shared__ float zz[DH];
    const int b = blockIdx.x, t = threadIdx.x;
    gz[t] = g[b * DH + t];
    __syncthreads();
    float s = bf2f(b1[t]);
    for (int k = 0; k < DH; ++k) s += gz[k] * bf2f(W1[k * DH + t]);
    zz[t] = fmaxf(s, 0.f);
    __syncthreads();
    if (t < NCLS) {
        float s2 = bf2f(b2[t]);
        for (int k = 0; k < DH; ++k) s2 += zz[k] * bf2f(W2[k * NCLS + t]);
        if (flag[0]) ((float*)outv)[b * NCLS + t] = s2;
        else ((unsigned short*)outv)[b * NCLS + t] = f2bf(s2);
    }
}

extern "C" void kernel_launch(void* const* d_in, const int* in_sizes, int n_in,
                              void* d_out, int out_size, void* d_ws, size_t ws_size,
                              hipStream_t stream)
{
    const void* x      = d_in[0];
    const int* ei      = (const int*)d_in[1];
    const int* batch   = (const int*)d_in[2];
    const void* Win    = d_in[3];
    const void* b_in   = d_in[4];
    const void* convW  = d_in[5];
    const void* convB  = d_in[6];
    const void* lnG    = d_in[7];
    const void* lnB    = d_in[8];
    const void* W1     = d_in[9];
    const void* b1     = d_in[10];
    const void* W2     = d_in[11];
    const void* b2     = d_in[12];

    // workspace layout (bytes), 16B aligned
    char* ws = (char*)d_ws;
    unsigned short* h   = (unsigned short*)(ws + 0);          // 25,600,000
    unsigned short* m   = (unsigned short*)(ws + 25600000);   // 25,600,000
    int* csrc           = (int*)(ws + 51200000);              //  3,200,000
    int* rowptr         = (int*)(ws + 54400000);              //    200,016
    int* cnt            = (int*)(ws + 54600016);              //    200,000
    int* cursor         = (int*)(ws + 54800016);              //    200,000
    float* dinv         = (float*)(ws + 55000016);            //    200,000
    unsigned short* cw  = (unsigned short*)(ws + 55200016);   //    138,768
    unsigned short* WinT= (unsigned short*)(ws + 55338784);   //    393,216
    unsigned short* WcT = (unsigned short*)(ws + 55732000);   //    393,216
    float* g            = (float*)(ws + 56125216);            //     65,536
    float* pg           = (float*)(ws + 56190752);            //    524,288
    int* gb             = (int*)(ws + 56715040);              //        272 (65 used)
    int* bsum           = (int*)(ws + 56715312);              //        800
    int* boff           = (int*)(ws + 56716112);              //        800
    int* flag           = (int*)(ws + 56716912);              //         16
    const size_t NEED   = 56716928;
    if (ws_size < NEED) {
        fill_sentinel<<<(out_size / 2 + 255) / 256, 256, 0, stream>>>((float*)d_out, out_size / 2);
        return;
    }

    // canonical small weights (bf16 element offsets within cw)
    unsigned short* cBin   = cw + 0;
    unsigned short* cConvB = cw + 256;
    unsigned short* cLnG   = cw + 1024;
    unsigned short* cLnB   = cw + 1792;
    unsigned short* cW1    = cw + 2560;
    unsigned short* cW2    = cw + 68096;
    unsigned short* cB1    = cw + 69120;
    unsigned short* cB2    = cw + 69376;

    detect_dtype<<<1, 256, 0, stream>>>((const unsigned short*)x, flag);

    // ---- CSR build (dst-sorted) + degrees ----
    hipMemsetAsync(cnt, 0, 400000, stream);  // cnt AND cursor (contiguous)
    count_edges<<<(NEDGES + 255) / 256, 256, 0, stream>>>(ei, cnt);
    scan_local<<<SCAN_BLOCKS, 256, 0, stream>>>(cnt, rowptr, bsum);
    scan_bsum<<<1, 256, 0, stream>>>(bsum, boff);
    scan_finish<<<SCAN_BLOCKS, 256, 0, stream>>>(rowptr, boff, cnt, dinv);
    fill_csr<<<(NEDGES + 255) / 256, 256, 0, stream>>>(ei, rowptr, cursor, csrc);

    // ---- weights: canon + convert/transpose ----
    canon_small<<<(69380 + 255) / 256, 256, 0, stream>>>(b_in, convB, lnG, lnB, W1, W2, b1, b2, cw, flag);
    transpose_win<<<(DIN * DH + 255) / 256, 256, 0, stream>>>(Win, WinT, flag);
    transpose_convw<<<(3 * DH * DH + 255) / 256, 256, 0, stream>>>(convW, WcT, flag);

    // ---- h = x @ W_in + b_in ----
    dim3 gg((NNODES + BM - 1) / BM, DH / BN);
    gemm_bf16_tn<<<gg, 256, 0, stream>>>(x, flag, 1, WinT, cBin, h, NNODES, DH, DIN);

    // ---- 3 GCN layers ----
    for (int i = 0; i < 3; i++) {
        gemm_bf16_tn<<<gg, 256, 0, stream>>>(h, flag, 0, WcT + i * DH * DH, nullptr, m,
                                             NNODES, DH, DH);
        aggregate_ln<<<NNODES / 8, 256, 0, stream>>>(
            rowptr, csrc, dinv, m, cConvB + i * DH, cLnG + i * DH, cLnB + i * DH, h);
    }

    // ---- global max pool + classifier ----
    find_bounds<<<(NNODES + 255) / 256, 256, 0, stream>>>(batch, gb);
    pool_partial<<<NGRAPHS * PSPLIT, 256, 0, stream>>>(h, gb, pg);
    pool_reduce<<<NGRAPHS, 256, 0, stream>>>(pg, g);
    classifier<<<NGRAPHS, 256, 0, stream>>>(g, cW1, cB1, cW2, cB2, d_out, flag);
}